// Round 1
// baseline (2776.296 us; speedup 1.0000x reference)
//
#include <hip/hip_runtime.h>
#include <stdint.h>

typedef unsigned short u16;
typedef __attribute__((ext_vector_type(8))) short short8v;
typedef __attribute__((ext_vector_type(4))) short short4v;
typedef __attribute__((ext_vector_type(4))) float f32x4;

#define CC 512
#define HD 256

__device__ __forceinline__ u16 f2bf(float f) {
  union { float f; uint32_t u; } v; v.f = f;
  return (u16)((v.u + 0x7FFFu + ((v.u >> 16) & 1u)) >> 16);
}
__device__ __forceinline__ float bf2f(u16 h) {
  union { uint32_t u; float f; } v; v.u = ((uint32_t)h) << 16;
  return v.f;
}
__device__ __forceinline__ float gelu_f(float x) {
  return 0.5f * x * (1.0f + erff(x * 0.7071067811865475f));
}

// ---------------- prep: bf16 transposed weights into ws (u16 elements) ------
//  WaT  [512][256] @ 0        (w1 rows   0..255, transposed: row n, col k)
//  WbT  [512][256] @ 131072   (w1 rows 256..511, transposed)
//  W2T  [256][512] @ 262144
//  U1T [1024][256] @ 393216
//  U2T  [256][1024]@ 655360     total 917504 u16 = 1.75 MB
__global__ void prep_weights(const float* __restrict__ w1, const float* __restrict__ w2,
                             const float* __restrict__ u1, const float* __restrict__ u2,
                             u16* __restrict__ ws) {
  int idx = blockIdx.x * blockDim.x + threadIdx.x;
  if (idx >= 917504) return;
  float val;
  if (idx < 131072)      { int n = idx >> 8, k = idx & 255; val = w1[k * 512 + n]; }
  else if (idx < 262144) { int i = idx - 131072, n = i >> 8, k = i & 255; val = w1[(256 + k) * 512 + n]; }
  else if (idx < 393216) { int i = idx - 262144, n = i >> 9, k = i & 511; val = w2[k * 256 + n]; }
  else if (idx < 655360) { int i = idx - 393216, n = i >> 8, k = i & 255; val = u1[k * 1024 + n]; }
  else                   { int i = idx - 655360, n = i >> 10, k = i & 1023; val = u2[k * 256 + n]; }
  ws[idx] = f2bf(val);
}

// ---------------- strip kernel ----------------------------------------------
// block = 512 thr (8 waves), grid = (16 strips, 256 batch). Strip = 32 rows.
#define SPQ 520   // padded LDS stride (bf16) for P/Q/act: +8 shifts banks by 4/row
#define SHS 264   // padded LDS stride (bf16) for h_in halo
#define Q_OFF   0
#define P_OFF   49920
#define H_OFF   83200
#define W1E_OFF 108544
#define B1_OFF  116736
#define SC_OFF  118784
#define STRIP_LDS 119808

__global__ __launch_bounds__(512) void strip_kernel(
    const float* __restrict__ hin, const float* __restrict__ xyz, const int* __restrict__ valid,
    const float* __restrict__ lnw, const float* __restrict__ lnb,
    const float* __restrict__ w1, const float* __restrict__ b1,
    const u16* __restrict__ WaT, const u16* __restrict__ WbT,
    const u16* __restrict__ W2T, const float* __restrict__ b2,
    float* __restrict__ out) {
  extern __shared__ char lds[];
  u16* sQ = (u16*)(lds + Q_OFF);     // [48][SPQ]
  u16* sP = (u16*)(lds + P_OFF);     // [32][SPQ], later act
  u16* sH = (u16*)(lds + H_OFF);     // [48][SHS]
  float* sW1e = (float*)(lds + W1E_OFF);  // [4][512]
  float* sB1  = (float*)(lds + B1_OFF);   // [512]
  float* sEx  = (float*)(lds + SC_OFF);   // 6 x [32]
  float* sEy = sEx + 32; float* sEz = sEx + 64; float* sEd = sEx + 96;
  float* sV = sEx + 128; float* sNV = sEx + 160;

  const int tid  = threadIdx.x;
  const int lane = tid & 63;
  const int wid  = tid >> 6;
  const int quad = lane >> 4;
  const int l16  = lane & 15;
  const int n    = blockIdx.y;
  const int c0   = blockIdx.x * 32;

  // stage edge-weight rows (w1 rows 512..515 are contiguous) and b1
  for (int i = tid; i < 2048; i += 512) sW1e[i] = w1[262144 + i];
  sB1[tid] = b1[tid & 511];

  // Phase 1: LayerNorm of 48 halo rows -> sH (bf16). wave w handles rows w*6..w*6+5
  for (int i = 0; i < 6; ++i) {
    const int r = wid * 6 + i;
    const int ch = c0 - 8 + r;
    float x0 = 0.f, x1 = 0.f, x2 = 0.f, x3 = 0.f;
    if (ch >= 0 && ch < CC) {
      const float* src = hin + (size_t)(n * CC + ch) * HD + lane * 4;
      x0 = src[0]; x1 = src[1]; x2 = src[2]; x3 = src[3];
    }
    float s = x0 + x1 + x2 + x3;
    float ss = x0*x0 + x1*x1 + x2*x2 + x3*x3;
    #pragma unroll
    for (int m = 1; m < 64; m <<= 1) { s += __shfl_xor(s, m, 64); ss += __shfl_xor(ss, m, 64); }
    const float mu = s * (1.f / 256.f);
    const float var = ss * (1.f / 256.f) - mu * mu;
    const float rstd = rsqrtf(var + 1e-5f);
    const int k4 = lane * 4;
    short4v pk;
    ((u16*)&pk)[0] = f2bf((x0 - mu) * rstd * lnw[k4 + 0] + lnb[k4 + 0]);
    ((u16*)&pk)[1] = f2bf((x1 - mu) * rstd * lnw[k4 + 1] + lnb[k4 + 1]);
    ((u16*)&pk)[2] = f2bf((x2 - mu) * rstd * lnw[k4 + 2] + lnb[k4 + 2]);
    ((u16*)&pk)[3] = f2bf((x3 - mu) * rstd * lnw[k4 + 3] + lnb[k4 + 3]);
    *(short4v*)&sH[r * SHS + k4] = pk;
  }
  __syncthreads();

  // Phase 2: P = h_strip @ Wa (64 tiles), Q = h_halo @ Wb (96 tiles), MFMA 16x16x32
  for (int t = wid; t < 160; t += 8) {
    const bool isP = (t < 64);
    const int id = isP ? t : (t - 64);
    const int mt = id >> 5;
    const int nt = id & 31;
    const int hrow = (isP ? (8 + mt * 16) : (mt * 16)) + l16;
    const u16* wrow = (isP ? WaT : WbT) + (nt * 16 + l16) * 256;
    const u16* arow = sH + hrow * SHS;
    f32x4 acc = {0.f, 0.f, 0.f, 0.f};
    #pragma unroll
    for (int ks = 0; ks < 8; ++ks) {
      const int k0 = ks * 32 + quad * 8;
      short8v a = *(const short8v*)(arow + k0);
      short8v b = *(const short8v*)(wrow + k0);
      acc = __builtin_amdgcn_mfma_f32_16x16x32_bf16(a, b, acc, 0, 0, 0);
    }
    u16* dst = isP ? sP : sQ;
    const int orow = mt * 16 + quad * 4;
    const int col = nt * 16 + l16;
    #pragma unroll
    for (int r = 0; r < 4; ++r) dst[(orow + r) * SPQ + col] = f2bf(acc[r]);
  }

  // Phase 3: 8 passes (off in {1,2,4,8} x {fwd,rev}); act accumulated in regs.
  // Thread owns (row c = tid>>4, k-lanes kl*4 + b*64, b=0..7) -> 32 floats.
  float accr[8][4];
  const int c  = tid >> 4;
  const int kl = tid & 15;
  for (int pass = 0; pass < 8; ++pass) {
    const int off = 1 << (pass >> 1);
    const bool fwd = ((pass & 1) == 0);
    __syncthreads();
    if (tid < 32) {
      const int cc_ = c0 + tid;
      const int other = fwd ? (cc_ + off) : (cc_ - off);
      const bool inb = (other >= 0) && (other < CC);
      const int oc = inb ? other : cc_;
      float vv = 0.f;
      if (inb && (valid[n * CC + cc_] != 0) && (valid[n * CC + oc] != 0)) vv = 1.f;
      const float* xo = xyz + (size_t)(n * CC + oc) * 3;
      const float* xc = xyz + (size_t)(n * CC + cc_) * 3;
      const float dx = xo[0] - xc[0], dy = xo[1] - xc[1], dz = xo[2] - xc[2];
      float dist = fmaxf(sqrtf(dx*dx + dy*dy + dz*dz), 1e-6f);
      const float rin = 1.f / dist;
      sEx[tid] = dx * rin; sEy[tid] = dy * rin; sEz[tid] = dz * rin; sEd[tid] = dist;
      sV[tid] = vv;
      sNV[tid] = (pass == 0) ? vv : (sNV[tid] + vv);
    }
    __syncthreads();
    const float ex = sEx[c], ey = sEy[c], ez = sEz[c], ed = sEd[c], vv = sV[c];
    const int qrow = c + (fwd ? off : -off) + 8;   // always in [0,48)
    const u16* prow = sP + c * SPQ;
    const u16* qrp  = sQ + qrow * SPQ;
    #pragma unroll
    for (int b = 0; b < 8; ++b) {
      const int k0 = kl * 4 + b * 64;
      short4v pp = *(const short4v*)(prow + k0);
      short4v qq = *(const short4v*)(qrp + k0);
      const float4 we0 = *(const float4*)&sW1e[k0];
      const float4 we1 = *(const float4*)&sW1e[512 + k0];
      const float4 we2 = *(const float4*)&sW1e[1024 + k0];
      const float4 we3 = *(const float4*)&sW1e[1536 + k0];
      const float4 bb  = *(const float4*)&sB1[k0];
      #pragma unroll
      for (int j = 0; j < 4; ++j) {
        float pre = bf2f(((u16*)&pp)[j]) + bf2f(((u16*)&qq)[j])
                  + ex * ((const float*)&we0)[j] + ey * ((const float*)&we1)[j]
                  + ez * ((const float*)&we2)[j] + ed * ((const float*)&we3)[j]
                  + ((const float*)&bb)[j];
        const float g = vv * gelu_f(pre);
        accr[b][j] = (pass == 0) ? g : (accr[b][j] + g);
      }
    }
  }
  __syncthreads();
  // write act (overwrites sP; P values are dead now)
  {
    u16* aw = sP + c * SPQ;
    #pragma unroll
    for (int b = 0; b < 8; ++b) {
      const int k0 = kl * 4 + b * 64;
      short4v pk;
      #pragma unroll
      for (int j = 0; j < 4; ++j) ((u16*)&pk)[j] = f2bf(accr[b][j]);
      *(short4v*)(aw + k0) = pk;
    }
  }
  __syncthreads();

  // Phase 4: agg = act(32x512) @ W2(512x256); out = h + (agg + b2*nv)*valid
  {
    const int mt = wid >> 2;
    const int ng = wid & 3;
    f32x4 zero4 = {0.f, 0.f, 0.f, 0.f};
    f32x4 macc[4] = {zero4, zero4, zero4, zero4};
    const u16* arow = sP + (mt * 16 + l16) * SPQ;
    #pragma unroll
    for (int ks = 0; ks < 16; ++ks) {
      const int k0 = ks * 32 + quad * 8;
      short8v a = *(const short8v*)(arow + k0);
      #pragma unroll
      for (int tt = 0; tt < 4; ++tt) {
        const int nn = (ng * 4 + tt) * 16 + l16;
        short8v b = *(const short8v*)(W2T + nn * 512 + k0);
        macc[tt] = __builtin_amdgcn_mfma_f32_16x16x32_bf16(a, b, macc[tt], 0, 0, 0);
      }
    }
    #pragma unroll
    for (int tt = 0; tt < 4; ++tt) {
      const int col = (ng * 4 + tt) * 16 + l16;
      const float b2v = b2[col];
      #pragma unroll
      for (int r = 0; r < 4; ++r) {
        const int cr = mt * 16 + quad * 4 + r;
        const int gc = c0 + cr;
        const float vown = (valid[n * CC + gc] != 0) ? 1.f : 0.f;
        const size_t gi = (size_t)(n * CC + gc) * HD + col;
        out[gi] = hin[gi] + (macc[tt][r] + b2v * sNV[cr]) * vown;
      }
    }
  }
}

// ---------------- update kernel: LN -> 256->1024 gelu -> 1024->256, in-place -
#define HN_S 260
#define X_S 264
#define Y_S 1032
#define HN_OFF 0
#define X_OFF 33280
#define Y_OFF 50176
#define UPD_LDS 116224

__global__ __launch_bounds__(512) void update_kernel(
    const float* __restrict__ lnw, const float* __restrict__ lnb,
    const u16* __restrict__ U1T, const float* __restrict__ bu1,
    const u16* __restrict__ U2T, const float* __restrict__ bu2,
    const int* __restrict__ valid, float* __restrict__ out) {
  extern __shared__ char lds[];
  float* sHN = (float*)(lds + HN_OFF);  // [32][HN_S] raw h_new
  u16* sX = (u16*)(lds + X_OFF);        // [32][X_S] LN'd bf16
  u16* sY = (u16*)(lds + Y_OFF);        // [32][Y_S] hidden bf16

  const int tid  = threadIdx.x;
  const int lane = tid & 63;
  const int wid  = tid >> 6;
  const int quad = lane >> 4;
  const int l16  = lane & 15;
  const int n    = blockIdx.y;
  const int c0   = blockIdx.x * 32;

  // Phase A: load h_new rows from out, LN -> sX; raw -> sHN
  for (int i = 0; i < 4; ++i) {
    const int r = wid * 4 + i;
    const int k4 = lane * 4;
    const float* src = out + (size_t)(n * CC + c0 + r) * HD + k4;
    const float x0 = src[0], x1 = src[1], x2 = src[2], x3 = src[3];
    float s = x0 + x1 + x2 + x3;
    float ss = x0*x0 + x1*x1 + x2*x2 + x3*x3;
    #pragma unroll
    for (int m = 1; m < 64; m <<= 1) { s += __shfl_xor(s, m, 64); ss += __shfl_xor(ss, m, 64); }
    const float mu = s * (1.f / 256.f);
    const float var = ss * (1.f / 256.f) - mu * mu;
    const float rstd = rsqrtf(var + 1e-5f);
    float4 rv; rv.x = x0; rv.y = x1; rv.z = x2; rv.w = x3;
    *(float4*)&sHN[r * HN_S + k4] = rv;
    short4v pk;
    ((u16*)&pk)[0] = f2bf((x0 - mu) * rstd * lnw[k4 + 0] + lnb[k4 + 0]);
    ((u16*)&pk)[1] = f2bf((x1 - mu) * rstd * lnw[k4 + 1] + lnb[k4 + 1]);
    ((u16*)&pk)[2] = f2bf((x2 - mu) * rstd * lnw[k4 + 2] + lnb[k4 + 2]);
    ((u16*)&pk)[3] = f2bf((x3 - mu) * rstd * lnw[k4 + 3] + lnb[k4 + 3]);
    *(short4v*)&sX[r * X_S + k4] = pk;
  }
  __syncthreads();

  // GEMM1: y = gelu(x @ u1 + bu1), M=32 N=1024 K=256
  for (int t = wid; t < 128; t += 8) {
    const int mt = t >> 6;
    const int nt = t & 63;
    const u16* arow = sX + (mt * 16 + l16) * X_S;
    const u16* brow = U1T + (nt * 16 + l16) * 256;
    f32x4 acc = {0.f, 0.f, 0.f, 0.f};
    #pragma unroll
    for (int ks = 0; ks < 8; ++ks) {
      const int k0 = ks * 32 + quad * 8;
      acc = __builtin_amdgcn_mfma_f32_16x16x32_bf16(*(const short8v*)(arow + k0),
                                                    *(const short8v*)(brow + k0), acc, 0, 0, 0);
    }
    const int col = nt * 16 + l16;
    const float bv = bu1[col];
    #pragma unroll
    for (int r = 0; r < 4; ++r)
      sY[(mt * 16 + quad * 4 + r) * Y_S + col] = f2bf(gelu_f(acc[r] + bv));
  }
  __syncthreads();

  // GEMM2 + epilogue: out = (h_new + y @ u2 + bu2) * valid
  {
    const int mt = wid >> 2;
    const int ng = wid & 3;
    f32x4 zero4 = {0.f, 0.f, 0.f, 0.f};
    f32x4 acc[4] = {zero4, zero4, zero4, zero4};
    const u16* arow = sY + (mt * 16 + l16) * Y_S;
    #pragma unroll
    for (int ks = 0; ks < 32; ++ks) {
      const int k0 = ks * 32 + quad * 8;
      short8v a = *(const short8v*)(arow + k0);
      #pragma unroll
      for (int tt = 0; tt < 4; ++tt) {
        const int nn = (ng * 4 + tt) * 16 + l16;
        short8v b = *(const short8v*)(U2T + nn * 1024 + k0);
        acc[tt] = __builtin_amdgcn_mfma_f32_16x16x32_bf16(a, b, acc[tt], 0, 0, 0);
      }
    }
    #pragma unroll
    for (int tt = 0; tt < 4; ++tt) {
      const int col = (ng * 4 + tt) * 16 + l16;
      const float bv = bu2[col];
      #pragma unroll
      for (int r = 0; r < 4; ++r) {
        const int row = mt * 16 + quad * 4 + r;
        const int gc = c0 + row;
        const float vown = (valid[n * CC + gc] != 0) ? 1.f : 0.f;
        out[(size_t)(n * CC + gc) * HD + col] = (sHN[row * HN_S + col] + acc[tt][r] + bv) * vown;
      }
    }
  }
}

// ---------------- launch ----------------------------------------------------
extern "C" void kernel_launch(void* const* d_in, const int* in_sizes, int n_in,
                              void* d_out, int out_size, void* d_ws, size_t ws_size,
                              hipStream_t stream) {
  (void)in_sizes; (void)n_in; (void)out_size; (void)ws_size;
  const float* h     = (const float*)d_in[0];
  const float* xyz   = (const float*)d_in[1];
  const int*   valid = (const int*)d_in[2];
  const float* lnnw  = (const float*)d_in[3];
  const float* lnnb  = (const float*)d_in[4];
  const float* w1    = (const float*)d_in[5];
  const float* b1    = (const float*)d_in[6];
  const float* w2    = (const float*)d_in[7];
  const float* b2    = (const float*)d_in[8];
  const float* lnuw  = (const float*)d_in[9];
  const float* lnub  = (const float*)d_in[10];
  const float* u1    = (const float*)d_in[11];
  const float* bu1   = (const float*)d_in[12];
  const float* u2    = (const float*)d_in[13];
  const float* bu2   = (const float*)d_in[14];
  float* out = (float*)d_out;
  u16* ws = (u16*)d_ws;

  hipFuncSetAttribute(reinterpret_cast<const void*>(strip_kernel),
                      hipFuncAttributeMaxDynamicSharedMemorySize, STRIP_LDS);
  hipFuncSetAttribute(reinterpret_cast<const void*>(update_kernel),
                      hipFuncAttributeMaxDynamicSharedMemorySize, UPD_LDS);

  prep_weights<<<dim3(3584), dim3(256), 0, stream>>>(w1, w2, u1, u2, ws);
  strip_kernel<<<dim3(16, 256), dim3(512), STRIP_LDS, stream>>>(
      h, xyz, valid, lnnw, lnnb, w1, b1, ws, ws + 131072, ws + 262144, b2, out);
  update_kernel<<<dim3(16, 256), dim3(512), UPD_LDS, stream>>>(
      lnuw, lnub, ws + 393216, bu1, ws + 655360, bu2, valid, out);
}

// Round 2
// 1510.801 us; speedup vs baseline: 1.8376x; 1.8376x over previous
//
#include <hip/hip_runtime.h>
#include <stdint.h>

typedef unsigned short u16;
typedef __attribute__((ext_vector_type(8))) short short8v;
typedef __attribute__((ext_vector_type(4))) short short4v;
typedef __attribute__((ext_vector_type(4))) float f32x4;

#define CC 512
#define HD 256

__device__ __forceinline__ u16 f2bf(float f) {
  union { float f; uint32_t u; } v; v.f = f;
  return (u16)((v.u + 0x7FFFu + ((v.u >> 16) & 1u)) >> 16);
}
__device__ __forceinline__ float bf2f(u16 h) {
  union { uint32_t u; float f; } v; v.u = ((uint32_t)h) << 16;
  return v.f;
}
// tanh-form gelu via HW exp2 + rcp: max abs err ~1e-3 (threshold is 0.289)
__device__ __forceinline__ float gelu_c(float x) {
  float x2 = x * x;
  float a  = x * fmaf(x2, 0.044715f, 1.0f);          // x + 0.044715 x^3
  float t  = __builtin_amdgcn_exp2f(a * -2.3022118f); // exp(-2*0.79788456*a)
  return x * __builtin_amdgcn_rcpf(1.0f + t);
}

// ---------------- prep: bf16 transposed weights into ws (u16 elements) ------
//  WaT  [512][256] @ 0        (w1 rows   0..255, transposed)
//  WbT  [512][256] @ 131072   (w1 rows 256..511, transposed)
//  W2T  [256][512] @ 262144
//  U1T [1024][256] @ 393216
//  U2T  [256][1024]@ 655360
__global__ void prep_weights(const float* __restrict__ w1, const float* __restrict__ w2,
                             const float* __restrict__ u1, const float* __restrict__ u2,
                             u16* __restrict__ ws) {
  int idx = blockIdx.x * blockDim.x + threadIdx.x;
  if (idx >= 917504) return;
  float val;
  if (idx < 131072)      { int n = idx >> 8, k = idx & 255; val = w1[k * 512 + n]; }
  else if (idx < 262144) { int i = idx - 131072, n = i >> 8, k = i & 255; val = w1[(256 + k) * 512 + n]; }
  else if (idx < 393216) { int i = idx - 262144, n = i >> 9, k = i & 511; val = w2[k * 256 + n]; }
  else if (idx < 655360) { int i = idx - 393216, n = i >> 8, k = i & 255; val = u1[k * 1024 + n]; }
  else                   { int i = idx - 655360, n = i >> 10, k = i & 1023; val = u2[k * 256 + n]; }
  ws[idx] = f2bf(val);
}

// ---------------- strip kernel: 16-row strips, 32-row halo ------------------
// block = 512 thr (8 waves), grid = (32 strips, 256 batch). LDS = 79,680 B
// -> 2 blocks/CU (16 waves/CU = 50% occ at <=128 VGPR).
#define SPQ 520   // u16 stride, mult of 8 (16B rows)
#define SHS 264
#define Q_OFF   0        // u16[32][520] = 33280 B
#define P_OFF   33280    // u16[16][520] = 16640 B
#define H_OFF   49920    // u16[32][264] = 16896 B ; act[16][520] overlays later
#define W1E_OFF 66816    // f32[4][512]  = 8192 B
#define B1_OFF  75008    // f32[512]     = 2048 B
#define EX_OFF  77056    // 5 x f32[8][16] = 2560 B
#define NV_OFF  79616    // f32[16]
#define STRIP_LDS 79680

__global__ __launch_bounds__(512) void strip_kernel(
    const float* __restrict__ hin, const float* __restrict__ xyz, const int* __restrict__ valid,
    const float* __restrict__ lnw, const float* __restrict__ lnb,
    const float* __restrict__ w1, const float* __restrict__ b1,
    const u16* __restrict__ WaT, const u16* __restrict__ WbT,
    const u16* __restrict__ W2T, const float* __restrict__ b2,
    float* __restrict__ out) {
  extern __shared__ char lds[];
  u16* sQ   = (u16*)(lds + Q_OFF);
  u16* sP   = (u16*)(lds + P_OFF);
  u16* sH   = (u16*)(lds + H_OFF);
  u16* sAct = (u16*)(lds + H_OFF);          // reuse after phase 2
  float* sW1e = (float*)(lds + W1E_OFF);
  float* sB1  = (float*)(lds + B1_OFF);
  float* sEx  = (float*)(lds + EX_OFF);     // [8][16]
  float* sEy = sEx + 128; float* sEz = sEx + 256;
  float* sEd = sEx + 384; float* sV  = sEx + 512;
  float* sNV = (float*)(lds + NV_OFF);

  const int tid  = threadIdx.x;
  const int lane = tid & 63;
  const int wid  = tid >> 6;
  const int quad = lane >> 4;
  const int l16  = lane & 15;
  const int n    = blockIdx.y;
  const int c0   = blockIdx.x * 16;

  // stage edge-weight rows of w1 (rows 512..515) and b1
  for (int i = tid; i < 2048; i += 512) sW1e[i] = w1[262144 + i];
  sB1[tid] = b1[tid];

  // edge scalars for all 8 passes x 16 rows
  if (tid < 128) {
    const int p = tid >> 4, r = tid & 15;
    const int off = 1 << (p >> 1);
    const bool fwd = ((p & 1) == 0);
    const int c = c0 + r;
    const int other = fwd ? (c + off) : (c - off);
    const bool inb = (other >= 0) && (other < CC);
    const int oc = inb ? other : c;
    float vv = 0.f;
    if (inb && (valid[n * CC + c] != 0) && (valid[n * CC + oc] != 0)) vv = 1.f;
    const float* xo = xyz + (size_t)(n * CC + oc) * 3;
    const float* xc = xyz + (size_t)(n * CC + c) * 3;
    const float dx = xo[0] - xc[0], dy = xo[1] - xc[1], dz = xo[2] - xc[2];
    const float dist = fmaxf(sqrtf(dx*dx + dy*dy + dz*dz), 1e-6f);
    const float rin = 1.f / dist;
    sEx[tid] = dx * rin; sEy[tid] = dy * rin; sEz[tid] = dz * rin;
    sEd[tid] = dist; sV[tid] = vv;
  }

  // Phase 1: LN of 32 halo rows (c0-8 .. c0+23) -> sH bf16. wave w: rows w*4..+3
  for (int i = 0; i < 4; ++i) {
    const int r = wid * 4 + i;
    const int ch = c0 - 8 + r;
    float x0 = 0.f, x1 = 0.f, x2 = 0.f, x3 = 0.f;
    if (ch >= 0 && ch < CC) {
      const float* src = hin + (size_t)(n * CC + ch) * HD + lane * 4;
      x0 = src[0]; x1 = src[1]; x2 = src[2]; x3 = src[3];
    }
    float s = x0 + x1 + x2 + x3;
    float ss = x0*x0 + x1*x1 + x2*x2 + x3*x3;
    #pragma unroll
    for (int m = 1; m < 64; m <<= 1) { s += __shfl_xor(s, m, 64); ss += __shfl_xor(ss, m, 64); }
    const float mu = s * (1.f / 256.f);
    const float rstd = rsqrtf(ss * (1.f / 256.f) - mu * mu + 1e-5f);
    const int k4 = lane * 4;
    short4v pk;
    ((u16*)&pk)[0] = f2bf((x0 - mu) * rstd * lnw[k4 + 0] + lnb[k4 + 0]);
    ((u16*)&pk)[1] = f2bf((x1 - mu) * rstd * lnw[k4 + 1] + lnb[k4 + 1]);
    ((u16*)&pk)[2] = f2bf((x2 - mu) * rstd * lnw[k4 + 2] + lnb[k4 + 2]);
    ((u16*)&pk)[3] = f2bf((x3 - mu) * rstd * lnw[k4 + 3] + lnb[k4 + 3]);
    *(short4v*)&sH[r * SHS + k4] = pk;
  }
  __syncthreads();

  // Phase 2: P = strip@Wa (1 mtile), Q = halo@Wb (2 mtiles); B-frags reg-resident
  if (tid < 16) {  // nv per row (sV written before barrier)
    float s = 0.f;
    #pragma unroll
    for (int p = 0; p < 8; ++p) s += sV[p * 16 + tid];
    sNV[tid] = s;
  }
  for (int nt = wid; nt < 32; nt += 8) {
    const int col = nt * 16 + l16;
    short8v bw[8];
    {
      const u16* bp = WaT + (size_t)col * 256;
      #pragma unroll
      for (int ks = 0; ks < 8; ++ks) bw[ks] = *(const short8v*)(bp + ks * 32 + quad * 8);
      const u16* ar = sH + (8 + l16) * SHS;
      f32x4 acc = {0.f, 0.f, 0.f, 0.f};
      #pragma unroll
      for (int ks = 0; ks < 8; ++ks)
        acc = __builtin_amdgcn_mfma_f32_16x16x32_bf16(*(const short8v*)(ar + ks * 32 + quad * 8), bw[ks], acc, 0, 0, 0);
      #pragma unroll
      for (int r = 0; r < 4; ++r) sP[(quad * 4 + r) * SPQ + col] = f2bf(acc[r]);
    }
    {
      const u16* bp = WbT + (size_t)col * 256;
      #pragma unroll
      for (int ks = 0; ks < 8; ++ks) bw[ks] = *(const short8v*)(bp + ks * 32 + quad * 8);
      #pragma unroll
      for (int mt = 0; mt < 2; ++mt) {
        const u16* ar = sH + (mt * 16 + l16) * SHS;
        f32x4 acc = {0.f, 0.f, 0.f, 0.f};
        #pragma unroll
        for (int ks = 0; ks < 8; ++ks)
          acc = __builtin_amdgcn_mfma_f32_16x16x32_bf16(*(const short8v*)(ar + ks * 32 + quad * 8), bw[ks], acc, 0, 0, 0);
        #pragma unroll
        for (int r = 0; r < 4; ++r) sQ[(mt * 16 + quad * 4 + r) * SPQ + col] = f2bf(acc[r]);
      }
    }
  }
  __syncthreads();

  // Phase 3: 8 passes; P hoisted to regs; skip invalid edges (vv==0 ~75%)
  const int row = tid >> 5;
  const int kl  = tid & 31;
  float accr[4][4];
  #pragma unroll
  for (int b = 0; b < 4; ++b)
    #pragma unroll
    for (int j = 0; j < 4; ++j) accr[b][j] = 0.f;
  short4v pp[4];
  {
    const u16* pr = sP + row * SPQ;
    #pragma unroll
    for (int b = 0; b < 4; ++b) pp[b] = *(const short4v*)(pr + kl * 4 + b * 128);
  }
  for (int pass = 0; pass < 8; ++pass) {
    const float vv = sV[pass * 16 + row];
    if (vv != 0.f) {
      const int off = 1 << (pass >> 1);
      const int doff = (pass & 1) ? -off : off;
      const float ex = sEx[pass * 16 + row], ey = sEy[pass * 16 + row];
      const float ez = sEz[pass * 16 + row], ed = sEd[pass * 16 + row];
      const u16* qr = sQ + (row + 8 + doff) * SPQ;
      #pragma unroll
      for (int b = 0; b < 4; ++b) {
        const int k0 = kl * 4 + b * 128;
        short4v qq = *(const short4v*)(qr + k0);
        const float4 we0 = *(const float4*)&sW1e[k0];
        const float4 we1 = *(const float4*)&sW1e[512 + k0];
        const float4 we2 = *(const float4*)&sW1e[1024 + k0];
        const float4 we3 = *(const float4*)&sW1e[1536 + k0];
        const float4 bb  = *(const float4*)&sB1[k0];
        #pragma unroll
        for (int j = 0; j < 4; ++j) {
          float pre = bf2f(((u16*)&pp[b])[j]) + bf2f(((u16*)&qq)[j])
                    + ex * ((const float*)&we0)[j] + ey * ((const float*)&we1)[j]
                    + ez * ((const float*)&we2)[j] + ed * ((const float*)&we3)[j]
                    + ((const float*)&bb)[j];
          accr[b][j] += gelu_c(pre);
        }
      }
    }
  }
  __syncthreads();
  {
    u16* aw = sAct + row * SPQ;
    #pragma unroll
    for (int b = 0; b < 4; ++b) {
      short4v pk;
      #pragma unroll
      for (int j = 0; j < 4; ++j) ((u16*)&pk)[j] = f2bf(accr[b][j]);
      *(short4v*)(aw + kl * 4 + b * 128) = pk;
    }
  }
  __syncthreads();

  // Phase 4: agg = act(16x512)@W2 ; out = h + (agg + b2*nv)*valid
  {
    const int nt0 = wid * 2, nt1 = wid * 2 + 1;
    const u16* b0p = W2T + (size_t)(nt0 * 16 + l16) * 512;
    const u16* b1p = W2T + (size_t)(nt1 * 16 + l16) * 512;
    f32x4 a0 = {0.f, 0.f, 0.f, 0.f}, a1 = {0.f, 0.f, 0.f, 0.f};
    #pragma unroll
    for (int ks = 0; ks < 16; ++ks) {
      short8v a = *(const short8v*)(sAct + l16 * SPQ + ks * 32 + quad * 8);
      a0 = __builtin_amdgcn_mfma_f32_16x16x32_bf16(a, *(const short8v*)(b0p + ks * 32 + quad * 8), a0, 0, 0, 0);
      a1 = __builtin_amdgcn_mfma_f32_16x16x32_bf16(a, *(const short8v*)(b1p + ks * 32 + quad * 8), a1, 0, 0, 0);
    }
    #pragma unroll
    for (int t = 0; t < 2; ++t) {
      const f32x4 av = t ? a1 : a0;
      const int col = (t ? nt1 : nt0) * 16 + l16;
      const float b2v = b2[col];
      #pragma unroll
      for (int r = 0; r < 4; ++r) {
        const int rw = quad * 4 + r;
        const int gc = c0 + rw;
        const float vown = (valid[n * CC + gc] != 0) ? 1.f : 0.f;
        const size_t gi = (size_t)(n * CC + gc) * HD + col;
        out[gi] = hin[gi] + (av[r] + b2v * sNV[rw]) * vown;
      }
    }
  }
}

// ---------------- update kernel: LN -> 256->1024 gelu -> 1024->256 ----------
// M=32 rows/block, hidden split into two 512 halves (split-K GEMM2 in regs).
// LDS = 50,176 B -> 2 blocks/CU.
#define X_S 264
#define Y_S 520
#define UX_OFF 0          // u16[32][264] = 16896
#define UY_OFF 16896      // u16[32][520] = 33280
#define UPD_LDS 50176

__global__ __launch_bounds__(512) void update_kernel(
    const float* __restrict__ lnw, const float* __restrict__ lnb,
    const u16* __restrict__ U1T, const float* __restrict__ bu1,
    const u16* __restrict__ U2T, const float* __restrict__ bu2,
    const int* __restrict__ valid, float* __restrict__ out) {
  extern __shared__ char lds[];
  u16* sX = (u16*)(lds + UX_OFF);
  u16* sY = (u16*)(lds + UY_OFF);

  const int tid  = threadIdx.x;
  const int lane = tid & 63;
  const int wid  = tid >> 6;
  const int quad = lane >> 4;
  const int l16  = lane & 15;
  const int n    = blockIdx.y;
  const int c0   = blockIdx.x * 32;

  // Phase A: LN(out rows) -> sX bf16
  for (int i = 0; i < 4; ++i) {
    const int r = wid * 4 + i;
    const int k4 = lane * 4;
    const float* src = out + (size_t)(n * CC + c0 + r) * HD + k4;
    const float x0 = src[0], x1 = src[1], x2 = src[2], x3 = src[3];
    float s = x0 + x1 + x2 + x3;
    float ss = x0*x0 + x1*x1 + x2*x2 + x3*x3;
    #pragma unroll
    for (int m = 1; m < 64; m <<= 1) { s += __shfl_xor(s, m, 64); ss += __shfl_xor(ss, m, 64); }
    const float mu = s * (1.f / 256.f);
    const float rstd = rsqrtf(ss * (1.f / 256.f) - mu * mu + 1e-5f);
    short4v pk;
    ((u16*)&pk)[0] = f2bf((x0 - mu) * rstd * lnw[k4 + 0] + lnb[k4 + 0]);
    ((u16*)&pk)[1] = f2bf((x1 - mu) * rstd * lnw[k4 + 1] + lnb[k4 + 1]);
    ((u16*)&pk)[2] = f2bf((x2 - mu) * rstd * lnw[k4 + 2] + lnb[k4 + 2]);
    ((u16*)&pk)[3] = f2bf((x3 - mu) * rstd * lnw[k4 + 3] + lnb[k4 + 3]);
    *(short4v*)&sX[r * X_S + k4] = pk;
  }
  __syncthreads();

  // GEMM2 accumulators held across both K-halves: wave owns nt pair x 2 mt
  const int nt0 = wid * 2, nt1 = wid * 2 + 1;
  f32x4 acc2[2][2];
  #pragma unroll
  for (int a = 0; a < 2; ++a)
    #pragma unroll
    for (int b = 0; b < 2; ++b) acc2[a][b] = (f32x4){0.f, 0.f, 0.f, 0.f};

  for (int half = 0; half < 2; ++half) {
    if (half) __syncthreads();   // protect sY before overwrite
    // GEMM1: X(32x256) @ U1T[half] -> gelu -> sY(32x512). Wave: 4 nt x 2 mt.
    for (int j = 0; j < 4; ++j) {
      const int nt = wid + j * 8;
      const int nrow = half * 512 + nt * 16 + l16;
      short8v bw[8];
      const u16* bp = U1T + (size_t)nrow * 256;
      #pragma unroll
      for (int ks = 0; ks < 8; ++ks) bw[ks] = *(const short8v*)(bp + ks * 32 + quad * 8);
      const float bv = bu1[nrow];
      #pragma unroll
      for (int mt = 0; mt < 2; ++mt) {
        const u16* ar = sX + (mt * 16 + l16) * X_S;
        f32x4 acc = {0.f, 0.f, 0.f, 0.f};
        #pragma unroll
        for (int ks = 0; ks < 8; ++ks)
          acc = __builtin_amdgcn_mfma_f32_16x16x32_bf16(*(const short8v*)(ar + ks * 32 + quad * 8), bw[ks], acc, 0, 0, 0);
        #pragma unroll
        for (int r = 0; r < 4; ++r)
          sY[(mt * 16 + quad * 4 + r) * Y_S + nt * 16 + l16] = f2bf(gelu_c(acc[r] + bv));
      }
    }
    __syncthreads();
    // GEMM2 partial: acc2 += Y(32x512) @ U2T[:, half*512 + ...]
    const u16* b0p = U2T + (size_t)(nt0 * 16 + l16) * 1024 + half * 512;
    const u16* b1p = U2T + (size_t)(nt1 * 16 + l16) * 1024 + half * 512;
    #pragma unroll
    for (int ks = 0; ks < 16; ++ks) {
      short8v aA = *(const short8v*)(sY + l16 * Y_S + ks * 32 + quad * 8);
      short8v aB = *(const short8v*)(sY + (16 + l16) * Y_S + ks * 32 + quad * 8);
      short8v b0 = *(const short8v*)(b0p + ks * 32 + quad * 8);
      short8v b1 = *(const short8v*)(b1p + ks * 32 + quad * 8);
      acc2[0][0] = __builtin_amdgcn_mfma_f32_16x16x32_bf16(aA, b0, acc2[0][0], 0, 0, 0);
      acc2[1][0] = __builtin_amdgcn_mfma_f32_16x16x32_bf16(aB, b0, acc2[1][0], 0, 0, 0);
      acc2[0][1] = __builtin_amdgcn_mfma_f32_16x16x32_bf16(aA, b1, acc2[0][1], 0, 0, 0);
      acc2[1][1] = __builtin_amdgcn_mfma_f32_16x16x32_bf16(aB, b1, acc2[1][1], 0, 0, 0);
    }
  }

  // Epilogue: out = (h_new + y@u2 + bu2) * valid  (h_new re-read from out; L1/L2 hit)
  #pragma unroll
  for (int mt = 0; mt < 2; ++mt) {
    #pragma unroll
    for (int t = 0; t < 2; ++t) {
      const int col = (t ? nt1 : nt0) * 16 + l16;
      const float bv = bu2[col];
      #pragma unroll
      for (int r = 0; r < 4; ++r) {
        const int rw = mt * 16 + quad * 4 + r;
        const int gc = c0 + rw;
        const float vown = (valid[n * CC + gc] != 0) ? 1.f : 0.f;
        const size_t gi = (size_t)(n * CC + gc) * HD + col;
        out[gi] = (out[gi] + acc2[mt][t][r] + bv) * vown;
      }
    }
  }
}

// ---------------- launch ----------------------------------------------------
extern "C" void kernel_launch(void* const* d_in, const int* in_sizes, int n_in,
                              void* d_out, int out_size, void* d_ws, size_t ws_size,
                              hipStream_t stream) {
  (void)in_sizes; (void)n_in; (void)out_size; (void)ws_size;
  const float* h     = (const float*)d_in[0];
  const float* xyz   = (const float*)d_in[1];
  const int*   valid = (const int*)d_in[2];
  const float* lnnw  = (const float*)d_in[3];
  const float* lnnb  = (const float*)d_in[4];
  const float* w1    = (const float*)d_in[5];
  const float* b1    = (const float*)d_in[6];
  const float* w2    = (const float*)d_in[7];
  const float* b2    = (const float*)d_in[8];
  const float* lnuw  = (const float*)d_in[9];
  const float* lnub  = (const float*)d_in[10];
  const float* u1    = (const float*)d_in[11];
  const float* bu1   = (const float*)d_in[12];
  const float* u2    = (const float*)d_in[13];
  const float* bu2   = (const float*)d_in[14];
  float* out = (float*)d_out;
  u16* ws = (u16*)d_ws;

  hipFuncSetAttribute(reinterpret_cast<const void*>(strip_kernel),
                      hipFuncAttributeMaxDynamicSharedMemorySize, STRIP_LDS);
  hipFuncSetAttribute(reinterpret_cast<const void*>(update_kernel),
                      hipFuncAttributeMaxDynamicSharedMemorySize, UPD_LDS);

  prep_weights<<<dim3(3584), dim3(256), 0, stream>>>(w1, w2, u1, u2, ws);
  strip_kernel<<<dim3(32, 256), dim3(512), STRIP_LDS, stream>>>(
      h, xyz, valid, lnnw, lnnb, w1, b1, ws, ws + 131072, ws + 262144, b2, out);
  update_kernel<<<dim3(16, 256), dim3(512), UPD_LDS, stream>>>(
      lnuw, lnub, ws + 393216, bu1, ws + 655360, bu2, valid, out);
}